// Round 1
// baseline (526.108 us; speedup 1.0000x reference)
//
#include <hip/hip_runtime.h>
#include <math.h>

// Problem constants (B,K,N,M) = (32,128,128,256)
#define Bb 32
#define Kk 128
#define Nn 128
#define Mm 256
#define EPS2 0.01f      // EPSILON^2
#define LAMBDA_S 0.1f
#define LR 0.01f
#define BN_EPS_C 1e-5f

// ---------------------------------------------------------------------------
// K0: scalars — total = sum(count), alpha[k] = c_alpha_k, alpha[128] = e_alpha,
// gama[k] = count/total. 1 block x 128 threads.
__global__ void k0_scalars(const float* __restrict__ cnt, float* __restrict__ alpha,
                           float* __restrict__ gama) {
  int t = threadIdx.x;  // 0..127
  float c = cnt[t];
  float s = c;
  #pragma unroll
  for (int o = 32; o > 0; o >>= 1) s += __shfl_down(s, o, 64);
  __shared__ float red[2];
  if ((t & 63) == 0) red[t >> 6] = s;
  __syncthreads();
  float total = red[0] + red[1];
  bool has = total > 1e-6f;
  float bk = (c != 0.0f) ? 1.0f : 0.0f;
  float cfix = c + (1.0f - bk);
  alpha[t] = (float)Nn / (cfix * EPS2) * bk;
  gama[t] = has ? (c / total) : 0.0f;
  if (t == 0) alpha[128] = has ? ((float)Nn / (EPS2 * total)) : 0.0f;
}

// ---------------------------------------------------------------------------
// K1: BatchNorm over (B, M) per channel n. grid 128, block 256 (one thread per m).
__global__ void k1_bn(const float* __restrict__ x, float* __restrict__ xn) {
  int n = blockIdx.x;
  int t = threadIdx.x;  // = m
  float s = 0.f, s2 = 0.f;
  #pragma unroll 4
  for (int b = 0; b < Bb; ++b) {
    float v = x[(size_t)b * (Nn * Mm) + n * Mm + t];
    s += v;
    s2 += v * v;
  }
  #pragma unroll
  for (int o = 32; o > 0; o >>= 1) {
    s += __shfl_down(s, o, 64);
    s2 += __shfl_down(s2, o, 64);
  }
  __shared__ float rs[4], rs2[4];
  if ((t & 63) == 0) { rs[t >> 6] = s; rs2[t >> 6] = s2; }
  __syncthreads();
  float S = rs[0] + rs[1] + rs[2] + rs[3];
  float S2 = rs2[0] + rs2[1] + rs2[2] + rs2[3];
  float mean = S * (1.0f / (Bb * Mm));
  float var = S2 * (1.0f / (Bb * Mm)) - mean * mean;
  float rstd = 1.0f / sqrtf(var + BN_EPS_C);
  #pragma unroll 4
  for (int b = 0; b < Bb; ++b) {
    size_t idx = (size_t)b * (Nn * Mm) + n * Mm + t;
    xn[idx] = (x[idx] - mean) * rstd;
  }
}

// ---------------------------------------------------------------------------
// K2a: Psum = sum_k EC_proto[k]. grid 64, block 256.
__global__ void k2a_psum(const float* __restrict__ P, float* __restrict__ Psum) {
  int e = blockIdx.x * 256 + threadIdx.x;
  float s = 0.f;
  #pragma unroll 8
  for (int k = 0; k < Kk; ++k) s += P[(size_t)k * 16384 + e];
  Psum[e] = s;
}

// K2b: D[b] = alpha[b]*src + I for b<128 (src=P[b]); b==128: src=Psum. grid 129.
__global__ void k2b_buildD(const float* __restrict__ P, const float* __restrict__ Psum,
                           const float* __restrict__ alpha, float* __restrict__ D) {
  int b = blockIdx.x;
  int t = threadIdx.x;
  float a = alpha[b];
  const float* src = (b < 128) ? (P + (size_t)b * 16384) : Psum;
  float* dst = D + (size_t)b * 16384;
  for (int c = 0; c < 64; ++c) {
    int e = c * 256 + t;
    int i = e >> 7, j = e & 127;
    dst[e] = a * src[e] + ((i == j) ? 1.0f : 0.0f);
  }
}

// ---------------------------------------------------------------------------
// K3: in-place Gauss-Jordan inverse of 129 matrices (128x128) in LDS,
// then scale by alpha[b] -> c_k (b<128) / e (b==128). grid 129, block 256.
__global__ __launch_bounds__(256, 1) void k3_invert(float* __restrict__ D,
                                                    const float* __restrict__ alpha) {
  __shared__ __align__(16) float A[128 * 128];  // 64 KB
  int blk = blockIdx.x;
  int t = threadIdx.x;
  float* mat = D + (size_t)blk * 16384;
  for (int c = 0; c < 64; ++c) A[c * 256 + t] = mat[c * 256 + t];
  int tx = t & 31;   // column quad: cols tx*4..tx*4+3
  int ty = t >> 5;   // 0..7: rows ty, ty+8, ..., ty+120
  __syncthreads();
  for (int p = 0; p < 128; ++p) {
    float piv = 1.0f / A[p * 128 + p];     // broadcast read
    float f[16];
    #pragma unroll
    for (int r = 0; r < 16; ++r) f[r] = A[(ty + 8 * r) * 128 + p];  // col p (2-addr bcast)
    __syncthreads();
    if (ty == 0) {  // scale pivot row; set A[p][p]=1 before scaling -> becomes piv
      float4 v = *(const float4*)&A[p * 128 + tx * 4];
      if ((p >> 2) == tx) ((float*)&v)[p & 3] = 1.0f;
      v.x *= piv; v.y *= piv; v.z *= piv; v.w *= piv;
      *(float4*)&A[p * 128 + tx * 4] = v;
    }
    __syncthreads();
    float4 prow = *(const float4*)&A[p * 128 + tx * 4];
    #pragma unroll
    for (int r = 0; r < 16; ++r) {
      int i = ty + 8 * r;
      if (i == p) continue;
      float4 v = *(const float4*)&A[i * 128 + tx * 4];
      v.x = fmaf(-f[r], prow.x, v.x);
      v.y = fmaf(-f[r], prow.y, v.y);
      v.z = fmaf(-f[r], prow.z, v.z);
      v.w = fmaf(-f[r], prow.w, v.w);
      // column p: computed f - f*piv, want -f*piv -> subtract f
      if ((p >> 2) == tx) ((float*)&v)[p & 3] -= f[r];
      *(float4*)&A[i * 128 + tx * 4] = v;
    }
    __syncthreads();
  }
  float a = alpha[blk];
  for (int c = 0; c < 64; ++c) mat[c * 256 + t] = a * A[c * 256 + t];
}

// ---------------------------------------------------------------------------
// K4: G_k = c_k^T c_k. grid 128, block 256 (16x16 threads, 8x8 outputs each).
__global__ __launch_bounds__(256, 1) void k4_gram(const float* __restrict__ C,
                                                  float* __restrict__ G) {
  __shared__ __align__(16) float A[128 * 128];  // full c_k, 64 KB
  int k = blockIdx.x;
  int t = threadIdx.x;
  const float* src = C + (size_t)k * 16384;
  for (int c = 0; c < 64; ++c) A[c * 256 + t] = src[c * 256 + t];
  __syncthreads();
  int tx = t & 15, ty = t >> 4;
  int i0 = ty * 8, j0 = tx * 8;
  float acc[8][8] = {};
  for (int l = 0; l < 128; ++l) {
    float ai[8], bj[8];
    *(float4*)&ai[0] = *(const float4*)&A[l * 128 + i0];
    *(float4*)&ai[4] = *(const float4*)&A[l * 128 + i0 + 4];
    *(float4*)&bj[0] = *(const float4*)&A[l * 128 + j0];
    *(float4*)&bj[4] = *(const float4*)&A[l * 128 + j0 + 4];
    #pragma unroll
    for (int qi = 0; qi < 8; ++qi)
      #pragma unroll
      for (int qj = 0; qj < 8; ++qj)
        acc[qi][qj] = fmaf(ai[qi], bj[qj], acc[qi][qj]);
  }
  float* dst = G + (size_t)k * 16384;
  #pragma unroll
  for (int qi = 0; qi < 8; ++qi) {
    float4 v0 = make_float4(acc[qi][0], acc[qi][1], acc[qi][2], acc[qi][3]);
    float4 v1 = make_float4(acc[qi][4], acc[qi][5], acc[qi][6], acc[qi][7]);
    *(float4*)&dst[(i0 + qi) * 128 + j0] = v0;
    *(float4*)&dst[(i0 + qi) * 128 + j0 + 4] = v1;
  }
}

// ---------------------------------------------------------------------------
// K5: S_b = xn_b xn_b^T. grid (32,2): col-half of 64. block 256 (8x4 outputs/thread).
__global__ __launch_bounds__(256, 1) void k5_S(const float* __restrict__ xn,
                                               float* __restrict__ S) {
  int b = blockIdx.x;
  int jbase = blockIdx.y * 64;
  __shared__ __align__(16) float X[128 * 65];  // 33.3 KB, pad 65 breaks conflicts
  int t = threadIdx.x;
  int tx = t & 15, ty = t >> 4;
  float acc[8][4] = {};
  for (int mc = 0; mc < Mm; mc += 64) {
    __syncthreads();
    for (int c = 0; c < 32; ++c) {
      int e = c * 256 + t;
      int i = e >> 6, mm = e & 63;
      X[i * 65 + mm] = xn[(size_t)b * (Nn * Mm) + i * Mm + mc + mm];
    }
    __syncthreads();
    for (int mm = 0; mm < 64; ++mm) {
      float ai[8], bj[4];
      #pragma unroll
      for (int q = 0; q < 8; ++q) ai[q] = X[(ty * 8 + q) * 65 + mm];
      #pragma unroll
      for (int q = 0; q < 4; ++q) bj[q] = X[(jbase + tx * 4 + q) * 65 + mm];
      #pragma unroll
      for (int qi = 0; qi < 8; ++qi)
        #pragma unroll
        for (int qj = 0; qj < 4; ++qj)
          acc[qi][qj] = fmaf(ai[qi], bj[qj], acc[qi][qj]);
    }
  }
  float* dst = S + (size_t)b * 16384;
  #pragma unroll
  for (int qi = 0; qi < 8; ++qi) {
    float4 v = make_float4(acc[qi][0], acc[qi][1], acc[qi][2], acc[qi][3]);
    *(float4*)&dst[(ty * 8 + qi) * 128 + jbase + tx * 4] = v;
  }
}

// ---------------------------------------------------------------------------
// K6: partial[c][b][k] = sum over inner chunk c (64 of 16384) of G[k][.]*S[b][.].
// grid 256, block 256.
__global__ __launch_bounds__(256, 1) void k6_partial(const float* __restrict__ G,
                                                     const float* __restrict__ S,
                                                     float* __restrict__ part) {
  int c = blockIdx.x;
  int t = threadIdx.x;
  __shared__ float Gp[128 * 65];  // 33.3 KB
  __shared__ float Sp[32 * 65];   // 8.3 KB
  int off = c * 64;
  for (int q = 0; q < 32; ++q) {
    int e = q * 256 + t;
    int k = e >> 6, jj = e & 63;
    Gp[k * 65 + jj] = G[(size_t)k * 16384 + off + jj];
  }
  for (int q = 0; q < 8; ++q) {
    int e = q * 256 + t;
    int b = e >> 6, jj = e & 63;
    Sp[b * 65 + jj] = S[(size_t)b * 16384 + off + jj];
  }
  __syncthreads();
  int tk = t & 15, tb = t >> 4;  // k = tk + 16q (bank-friendly), b = tb*2 + bb
  float acc[2][8] = {};
  for (int jj = 0; jj < 64; ++jj) {
    float sv0 = Sp[(tb * 2) * 65 + jj];
    float sv1 = Sp[(tb * 2 + 1) * 65 + jj];
    float gv[8];
    #pragma unroll
    for (int q = 0; q < 8; ++q) gv[q] = Gp[(tk + 16 * q) * 65 + jj];
    #pragma unroll
    for (int q = 0; q < 8; ++q) {
      acc[0][q] = fmaf(sv0, gv[q], acc[0][q]);
      acc[1][q] = fmaf(sv1, gv[q], acc[1][q]);
    }
  }
  float* pout = part + (size_t)c * 4096;
  #pragma unroll
  for (int bb = 0; bb < 2; ++bb)
    #pragma unroll
    for (int q = 0; q < 8; ++q)
      pout[(tb * 2 + bb) * 128 + tk + 16 * q] = acc[bb][q];
}

// ---------------------------------------------------------------------------
// K7: reduce partials -> norm -> rescale to sum 10 -> softmax -> w[k][b]=gama*pi.
// grid 32 (one per b), block 256 (two c-halves per k; duplicated softmax math).
__global__ void k7_weights(const float* __restrict__ part, const float* __restrict__ gama,
                           const float* __restrict__ cnt, float* __restrict__ wT) {
  int b = blockIdx.x;
  int t = threadIdx.x;
  int k = t & 127, h = t >> 7;
  float s = 0.f;
  #pragma unroll 8
  for (int c = h * 128; c < h * 128 + 128; ++c)
    s += part[(size_t)c * 4096 + b * 128 + k];
  __shared__ float sh[256];
  sh[t] = s;
  __syncthreads();
  float norm2 = sh[k] + sh[k + 128];  // both halves compute identical values
  float norm = sqrtf(fmaxf(norm2, 0.0f));
  // sum over 256 threads = 2 * (sum over k)
  float r = norm;
  #pragma unroll
  for (int o = 32; o > 0; o >>= 1) r += __shfl_down(r, o, 64);
  __shared__ float red[4];
  if ((t & 63) == 0) red[t >> 6] = r;
  __syncthreads();
  float sumn = 0.5f * (red[0] + red[1] + red[2] + red[3]);
  float nr = 10.0f * norm / fmaxf(sumn, 1e-30f);
  float ex = expf(-LAMBDA_S * nr);
  float r2 = ex;
  #pragma unroll
  for (int o = 32; o > 0; o >>= 1) r2 += __shfl_down(r2, o, 64);
  __shared__ float red2[4];
  if ((t & 63) == 0) red2[t >> 6] = r2;
  __syncthreads();
  float sume = 0.5f * (red2[0] + red2[1] + red2[2] + red2[3]);
  float bk = (cnt[k] != 0.0f) ? 1.0f : 0.0f;
  float pi = (ex / sume) * bk;
  if (h == 0) wT[k * 32 + b] = gama[k] * pi;  // transposed for K8 scalar loads
}

// ---------------------------------------------------------------------------
// K8: F[b] = e - sum_k w[b][k] * c_k. grid 64, block 256; each thread one (i,j),
// 32 accumulators (one per b).
__global__ __launch_bounds__(256, 1) void k8_F(const float* __restrict__ C,
                                               const float* __restrict__ E,
                                               const float* __restrict__ wT,
                                               float* __restrict__ F) {
  int e = blockIdx.x * 256 + threadIdx.x;
  float acc[32];
  float ev = E[e];
  #pragma unroll
  for (int b = 0; b < 32; ++b) acc[b] = ev;
  for (int k = 0; k < 128; ++k) {
    float cv = C[(size_t)k * 16384 + e];
    const float* wk = wT + k * 32;  // uniform -> s_load
    #pragma unroll
    for (int b = 0; b < 32; ++b) acc[b] = fmaf(-wk[b], cv, acc[b]);
  }
  #pragma unroll
  for (int b = 0; b < 32; ++b) F[(size_t)b * 16384 + e] = acc[b];
}

// ---------------------------------------------------------------------------
// K9: out[b] = xn[b] + LR * F[b] @ xn[b]. grid (32,4): m-quarter of 64. block 256.
__global__ __launch_bounds__(256, 1) void k9_out(const float* __restrict__ F,
                                                 const float* __restrict__ xn,
                                                 float* __restrict__ out) {
  int b = blockIdx.x;
  int mq = blockIdx.y;
  __shared__ __align__(16) float Ft[128 * 65];  // 33.3 KB
  __shared__ __align__(16) float Xt[64 * 65];   // 16.6 KB
  int t = threadIdx.x;
  int tx = t & 15, ty = t >> 4;
  int i0 = ty * 8, m0 = mq * 64 + tx * 4;
  float acc[8][4] = {};
  for (int jc = 0; jc < 128; jc += 64) {
    __syncthreads();
    for (int q = 0; q < 32; ++q) {
      int e = q * 256 + t;
      int i = e >> 6, jj = e & 63;
      Ft[i * 65 + jj] = F[(size_t)b * 16384 + i * 128 + jc + jj];
    }
    for (int q = 0; q < 16; ++q) {
      int e = q * 256 + t;
      int jj = e >> 6, mm = e & 63;
      Xt[jj * 65 + mm] = xn[(size_t)b * (Nn * Mm) + (jc + jj) * Mm + mq * 64 + mm];
    }
    __syncthreads();
    for (int jj = 0; jj < 64; ++jj) {
      float fi[8], xm[4];
      #pragma unroll
      for (int q = 0; q < 8; ++q) fi[q] = Ft[(i0 + q) * 65 + jj];
      #pragma unroll
      for (int q = 0; q < 4; ++q) xm[q] = Xt[jj * 65 + tx * 4 + q];
      #pragma unroll
      for (int qi = 0; qi < 8; ++qi)
        #pragma unroll
        for (int qj = 0; qj < 4; ++qj)
          acc[qi][qj] = fmaf(fi[qi], xm[qj], acc[qi][qj]);
    }
  }
  #pragma unroll
  for (int qi = 0; qi < 8; ++qi) {
    int i = i0 + qi;
    float4 xv = *(const float4*)&xn[(size_t)b * (Nn * Mm) + i * Mm + m0];
    float4 o;
    o.x = fmaf(LR, acc[qi][0], xv.x);
    o.y = fmaf(LR, acc[qi][1], xv.y);
    o.z = fmaf(LR, acc[qi][2], xv.z);
    o.w = fmaf(LR, acc[qi][3], xv.w);
    *(float4*)&out[(size_t)b * (Nn * Mm) + i * Mm + m0] = o;
  }
}

// ---------------------------------------------------------------------------
extern "C" void kernel_launch(void* const* d_in, const int* in_sizes, int n_in,
                              void* d_out, int out_size, void* d_ws, size_t ws_size,
                              hipStream_t stream) {
  const float* x = (const float*)d_in[0];     // (32,128,256)
  const float* P = (const float*)d_in[1];     // (128,128,128) EC_proto
  const float* cnt = (const float*)d_in[2];   // (128,)
  float* out = (float*)d_out;

  float* ws = (float*)d_ws;
  float* xn = ws;                               // 1048576
  float* C = xn + 1048576;                      // 129*16384 = 2113536 (c_k; slot 128 = e)
  float* G = C + 2113536;                       // 2097152
  float* S = G + 2097152;                       // 524288
  float* part = S + 524288;                     // 1048576
  float* F = part + 1048576;                    // 524288
  float* wT = F + 524288;                       // 4096
  float* Psum = wT + 4096;                      // 16384
  float* alpha = Psum + 16384;                  // 129
  float* gama = alpha + 129;                    // 128
  size_t need_bytes = (size_t)((gama + 128) - ws) * sizeof(float);
  if (ws_size < need_bytes) return;  // ~29.5 MB required

  hipLaunchKernelGGL(k0_scalars, dim3(1), dim3(128), 0, stream, cnt, alpha, gama);
  hipLaunchKernelGGL(k1_bn, dim3(128), dim3(256), 0, stream, x, xn);
  hipLaunchKernelGGL(k2a_psum, dim3(64), dim3(256), 0, stream, P, Psum);
  hipLaunchKernelGGL(k2b_buildD, dim3(129), dim3(256), 0, stream, P, Psum, alpha, C);
  hipLaunchKernelGGL(k3_invert, dim3(129), dim3(256), 0, stream, C, alpha);
  hipLaunchKernelGGL(k4_gram, dim3(128), dim3(256), 0, stream, C, G);
  hipLaunchKernelGGL(k5_S, dim3(32, 2), dim3(256), 0, stream, xn, S);
  hipLaunchKernelGGL(k6_partial, dim3(256), dim3(256), 0, stream, G, S, part);
  hipLaunchKernelGGL(k7_weights, dim3(32), dim3(256), 0, stream, part, gama, cnt, wT);
  hipLaunchKernelGGL(k8_F, dim3(64), dim3(256), 0, stream, C, C + (size_t)128 * 16384, wT, F);
  hipLaunchKernelGGL(k9_out, dim3(32, 4), dim3(256), 0, stream, F, xn, out);
}

// Round 2
// 383.513 us; speedup vs baseline: 1.3718x; 1.3718x over previous
//
#include <hip/hip_runtime.h>
#include <math.h>

// Problem constants (B,K,N,M) = (32,128,128,256)
#define Bb 32
#define Kk 128
#define Nn 128
#define Mm 256
#define EPS2 0.01f      // EPSILON^2
#define LAMBDA_S 0.1f
#define LR 0.01f
#define BN_EPS_C 1e-5f

// ---------------------------------------------------------------------------
// K0: scalars — total = sum(count), alpha[k] = c_alpha_k, alpha[128] = e_alpha,
// gama[k] = count/total. 1 block x 128 threads.
__global__ void k0_scalars(const float* __restrict__ cnt, float* __restrict__ alpha,
                           float* __restrict__ gama) {
  int t = threadIdx.x;  // 0..127
  float c = cnt[t];
  float s = c;
  #pragma unroll
  for (int o = 32; o > 0; o >>= 1) s += __shfl_down(s, o, 64);
  __shared__ float red[2];
  if ((t & 63) == 0) red[t >> 6] = s;
  __syncthreads();
  float total = red[0] + red[1];
  bool has = total > 1e-6f;
  float bk = (c != 0.0f) ? 1.0f : 0.0f;
  float cfix = c + (1.0f - bk);
  alpha[t] = (float)Nn / (cfix * EPS2) * bk;
  gama[t] = has ? (c / total) : 0.0f;
  if (t == 0) alpha[128] = has ? ((float)Nn / (EPS2 * total)) : 0.0f;
}

// ---------------------------------------------------------------------------
// K1: BatchNorm over (B, M) per channel n. grid 128, block 256 (one thread per m).
__global__ void k1_bn(const float* __restrict__ x, float* __restrict__ xn) {
  int n = blockIdx.x;
  int t = threadIdx.x;  // = m
  float s = 0.f, s2 = 0.f;
  #pragma unroll 4
  for (int b = 0; b < Bb; ++b) {
    float v = x[(size_t)b * (Nn * Mm) + n * Mm + t];
    s += v;
    s2 += v * v;
  }
  #pragma unroll
  for (int o = 32; o > 0; o >>= 1) {
    s += __shfl_down(s, o, 64);
    s2 += __shfl_down(s2, o, 64);
  }
  __shared__ float rs[4], rs2[4];
  if ((t & 63) == 0) { rs[t >> 6] = s; rs2[t >> 6] = s2; }
  __syncthreads();
  float S = rs[0] + rs[1] + rs[2] + rs[3];
  float S2 = rs2[0] + rs2[1] + rs2[2] + rs2[3];
  float mean = S * (1.0f / (Bb * Mm));
  float var = S2 * (1.0f / (Bb * Mm)) - mean * mean;
  float rstd = 1.0f / sqrtf(var + BN_EPS_C);
  #pragma unroll 4
  for (int b = 0; b < Bb; ++b) {
    size_t idx = (size_t)b * (Nn * Mm) + n * Mm + t;
    xn[idx] = (x[idx] - mean) * rstd;
  }
}

// ---------------------------------------------------------------------------
// K2a: Psum = sum_k EC_proto[k]. grid 64, block 256.
__global__ void k2a_psum(const float* __restrict__ P, float* __restrict__ Psum) {
  int e = blockIdx.x * 256 + threadIdx.x;
  float s = 0.f;
  #pragma unroll 8
  for (int k = 0; k < Kk; ++k) s += P[(size_t)k * 16384 + e];
  Psum[e] = s;
}

// K2b: D[b] = alpha[b]*src + I for b<128 (src=P[b]); b==128: src=Psum. grid 129.
__global__ void k2b_buildD(const float* __restrict__ P, const float* __restrict__ Psum,
                           const float* __restrict__ alpha, float* __restrict__ D) {
  int b = blockIdx.x;
  int t = threadIdx.x;
  float a = alpha[b];
  const float* src = (b < 128) ? (P + (size_t)b * 16384) : Psum;
  float* dst = D + (size_t)b * 16384;
  for (int c = 0; c < 64; ++c) {
    int e = c * 256 + t;
    int i = e >> 7, j = e & 127;
    dst[e] = a * src[e] + ((i == j) ? 1.0f : 0.0f);
  }
}

// ---------------------------------------------------------------------------
// K3 v2: register-resident Gauss-Jordan. Thread t owns row r=t>>1, col-half
// h=t&1 (64 floats in VGPRs). Per step only pivot row/col cross threads via
// tiny LDS buffers. p-loop template-unrolled -> all register indices static.
// Pivot-row scaling folds into the main FMA via g = (r==P) ? 1-pinv : f*pinv.
// 2 syncs/step. grid 129, block 256.
template<int P>
__device__ __forceinline__ void gj_step(float a[64], int r, int h,
                                        float* prow, float* fcol) {
  constexpr int HP = P >> 6;   // which column-half holds col P
  constexpr int JP = P & 63;   // local index of col P in that half
  // Phase 1: publish pivot column entry (own row) and pivot row (2 lanes).
  if (h == HP) fcol[r] = a[JP];
  if (r == P) {
    #pragma unroll
    for (int q = 0; q < 16; ++q)
      *(float4*)&prow[h * 64 + 4 * q] =
          make_float4(a[4 * q], a[4 * q + 1], a[4 * q + 2], a[4 * q + 3]);
  }
  __syncthreads();
  float piv = fcol[P];          // broadcast
  float pinv = 1.0f / piv;
  float f = fcol[r];            // A[r][P] (old)
  float g = (r == P) ? (1.0f - pinv) : f * pinv;
  const float4* pr4 = (const float4*)&prow[h * 64];
  #pragma unroll
  for (int q = 0; q < 16; ++q) {
    float4 pq = pr4[q];         // same-address broadcast per half -> conflict-free
    a[4 * q + 0] = fmaf(-g, pq.x, a[4 * q + 0]);
    a[4 * q + 1] = fmaf(-g, pq.y, a[4 * q + 1]);
    a[4 * q + 2] = fmaf(-g, pq.z, a[4 * q + 2]);
    a[4 * q + 3] = fmaf(-g, pq.w, a[4 * q + 3]);
  }
  if (h == HP) a[JP] = (r == P) ? pinv : -g;  // col-P / diagonal fixup
  __syncthreads();  // protect prow/fcol from next step's phase-1 writes
}

template<int P>
__device__ __forceinline__ void gj_rec(float a[64], int r, int h,
                                       float* prow, float* fcol) {
  if constexpr (P < 128) {
    gj_step<P>(a, r, h, prow, fcol);
    gj_rec<P + 1>(a, r, h, prow, fcol);
  }
}

__global__ __launch_bounds__(256, 1) void k3_invert(float* __restrict__ D,
                                                    const float* __restrict__ alpha) {
  __shared__ __align__(16) float prow[128];
  __shared__ float fcol[128];
  int blk = blockIdx.x;
  int t = threadIdx.x;
  int r = t >> 1;   // row 0..127
  int h = t & 1;    // column half
  // t*64 == r*128 + h*64: each lane's 64 floats are contiguous; the 16 quad
  // loads of a wave tile a contiguous 64KB region -> cache-line-complete.
  float* mat = D + (size_t)blk * 16384 + (size_t)t * 64;
  float a[64];
  #pragma unroll
  for (int q = 0; q < 16; ++q)
    *(float4*)&a[4 * q] = *(const float4*)&mat[4 * q];
  gj_rec<0>(a, r, h, prow, fcol);
  float al = alpha[blk];
  #pragma unroll
  for (int q = 0; q < 16; ++q) {
    float4 v = make_float4(al * a[4 * q], al * a[4 * q + 1],
                           al * a[4 * q + 2], al * a[4 * q + 3]);
    *(float4*)&mat[4 * q] = v;
  }
}

// ---------------------------------------------------------------------------
// K4: G_k = c_k^T c_k. grid 128, block 256 (16x16 threads, 8x8 outputs each).
__global__ __launch_bounds__(256, 1) void k4_gram(const float* __restrict__ C,
                                                  float* __restrict__ G) {
  __shared__ __align__(16) float A[128 * 128];  // full c_k, 64 KB
  int k = blockIdx.x;
  int t = threadIdx.x;
  const float* src = C + (size_t)k * 16384;
  for (int c = 0; c < 64; ++c) A[c * 256 + t] = src[c * 256 + t];
  __syncthreads();
  int tx = t & 15, ty = t >> 4;
  int i0 = ty * 8, j0 = tx * 8;
  float acc[8][8] = {};
  for (int l = 0; l < 128; ++l) {
    float ai[8], bj[8];
    *(float4*)&ai[0] = *(const float4*)&A[l * 128 + i0];
    *(float4*)&ai[4] = *(const float4*)&A[l * 128 + i0 + 4];
    *(float4*)&bj[0] = *(const float4*)&A[l * 128 + j0];
    *(float4*)&bj[4] = *(const float4*)&A[l * 128 + j0 + 4];
    #pragma unroll
    for (int qi = 0; qi < 8; ++qi)
      #pragma unroll
      for (int qj = 0; qj < 8; ++qj)
        acc[qi][qj] = fmaf(ai[qi], bj[qj], acc[qi][qj]);
  }
  float* dst = G + (size_t)k * 16384;
  #pragma unroll
  for (int qi = 0; qi < 8; ++qi) {
    float4 v0 = make_float4(acc[qi][0], acc[qi][1], acc[qi][2], acc[qi][3]);
    float4 v1 = make_float4(acc[qi][4], acc[qi][5], acc[qi][6], acc[qi][7]);
    *(float4*)&dst[(i0 + qi) * 128 + j0] = v0;
    *(float4*)&dst[(i0 + qi) * 128 + j0 + 4] = v1;
  }
}

// ---------------------------------------------------------------------------
// K5: S_b = xn_b xn_b^T. grid (32,2): col-half of 64. block 256 (8x4 outputs/thread).
__global__ __launch_bounds__(256, 1) void k5_S(const float* __restrict__ xn,
                                               float* __restrict__ S) {
  int b = blockIdx.x;
  int jbase = blockIdx.y * 64;
  __shared__ __align__(16) float X[128 * 65];  // 33.3 KB, pad 65 breaks conflicts
  int t = threadIdx.x;
  int tx = t & 15, ty = t >> 4;
  float acc[8][4] = {};
  for (int mc = 0; mc < Mm; mc += 64) {
    __syncthreads();
    for (int c = 0; c < 32; ++c) {
      int e = c * 256 + t;
      int i = e >> 6, mm = e & 63;
      X[i * 65 + mm] = xn[(size_t)b * (Nn * Mm) + i * Mm + mc + mm];
    }
    __syncthreads();
    for (int mm = 0; mm < 64; ++mm) {
      float ai[8], bj[4];
      #pragma unroll
      for (int q = 0; q < 8; ++q) ai[q] = X[(ty * 8 + q) * 65 + mm];
      #pragma unroll
      for (int q = 0; q < 4; ++q) bj[q] = X[(jbase + tx * 4 + q) * 65 + mm];
      #pragma unroll
      for (int qi = 0; qi < 8; ++qi)
        #pragma unroll
        for (int qj = 0; qj < 4; ++qj)
          acc[qi][qj] = fmaf(ai[qi], bj[qj], acc[qi][qj]);
    }
  }
  float* dst = S + (size_t)b * 16384;
  #pragma unroll
  for (int qi = 0; qi < 8; ++qi) {
    float4 v = make_float4(acc[qi][0], acc[qi][1], acc[qi][2], acc[qi][3]);
    *(float4*)&dst[(ty * 8 + qi) * 128 + jbase + tx * 4] = v;
  }
}

// ---------------------------------------------------------------------------
// K6: partial[c][b][k] = sum over inner chunk c (64 of 16384) of G[k][.]*S[b][.].
// grid 256, block 256.
__global__ __launch_bounds__(256, 1) void k6_partial(const float* __restrict__ G,
                                                     const float* __restrict__ S,
                                                     float* __restrict__ part) {
  int c = blockIdx.x;
  int t = threadIdx.x;
  __shared__ float Gp[128 * 65];  // 33.3 KB
  __shared__ float Sp[32 * 65];   // 8.3 KB
  int off = c * 64;
  for (int q = 0; q < 32; ++q) {
    int e = q * 256 + t;
    int k = e >> 6, jj = e & 63;
    Gp[k * 65 + jj] = G[(size_t)k * 16384 + off + jj];
  }
  for (int q = 0; q < 8; ++q) {
    int e = q * 256 + t;
    int b = e >> 6, jj = e & 63;
    Sp[b * 65 + jj] = S[(size_t)b * 16384 + off + jj];
  }
  __syncthreads();
  int tk = t & 15, tb = t >> 4;  // k = tk + 16q (bank-friendly), b = tb*2 + bb
  float acc[2][8] = {};
  for (int jj = 0; jj < 64; ++jj) {
    float sv0 = Sp[(tb * 2) * 65 + jj];
    float sv1 = Sp[(tb * 2 + 1) * 65 + jj];
    float gv[8];
    #pragma unroll
    for (int q = 0; q < 8; ++q) gv[q] = Gp[(tk + 16 * q) * 65 + jj];
    #pragma unroll
    for (int q = 0; q < 8; ++q) {
      acc[0][q] = fmaf(sv0, gv[q], acc[0][q]);
      acc[1][q] = fmaf(sv1, gv[q], acc[1][q]);
    }
  }
  float* pout = part + (size_t)c * 4096;
  #pragma unroll
  for (int bb = 0; bb < 2; ++bb)
    #pragma unroll
    for (int q = 0; q < 8; ++q)
      pout[(tb * 2 + bb) * 128 + tk + 16 * q] = acc[bb][q];
}

// ---------------------------------------------------------------------------
// K7: reduce partials -> norm -> rescale to sum 10 -> softmax -> w[k][b]=gama*pi.
// grid 32 (one per b), block 256 (two c-halves per k; duplicated softmax math).
__global__ void k7_weights(const float* __restrict__ part, const float* __restrict__ gama,
                           const float* __restrict__ cnt, float* __restrict__ wT) {
  int b = blockIdx.x;
  int t = threadIdx.x;
  int k = t & 127, h = t >> 7;
  float s = 0.f;
  #pragma unroll 8
  for (int c = h * 128; c < h * 128 + 128; ++c)
    s += part[(size_t)c * 4096 + b * 128 + k];
  __shared__ float sh[256];
  sh[t] = s;
  __syncthreads();
  float norm2 = sh[k] + sh[k + 128];  // both halves compute identical values
  float norm = sqrtf(fmaxf(norm2, 0.0f));
  // sum over 256 threads = 2 * (sum over k)
  float r = norm;
  #pragma unroll
  for (int o = 32; o > 0; o >>= 1) r += __shfl_down(r, o, 64);
  __shared__ float red[4];
  if ((t & 63) == 0) red[t >> 6] = r;
  __syncthreads();
  float sumn = 0.5f * (red[0] + red[1] + red[2] + red[3]);
  float nr = 10.0f * norm / fmaxf(sumn, 1e-30f);
  float ex = expf(-LAMBDA_S * nr);
  float r2 = ex;
  #pragma unroll
  for (int o = 32; o > 0; o >>= 1) r2 += __shfl_down(r2, o, 64);
  __shared__ float red2[4];
  if ((t & 63) == 0) red2[t >> 6] = r2;
  __syncthreads();
  float sume = 0.5f * (red2[0] + red2[1] + red2[2] + red2[3]);
  float bk = (cnt[k] != 0.0f) ? 1.0f : 0.0f;
  float pi = (ex / sume) * bk;
  if (h == 0) wT[k * 32 + b] = gama[k] * pi;  // transposed for K8 scalar loads
}

// ---------------------------------------------------------------------------
// K8: F[b] = e - sum_k w[b][k] * c_k. grid 64, block 256; each thread one (i,j),
// 32 accumulators (one per b).
__global__ __launch_bounds__(256, 1) void k8_F(const float* __restrict__ C,
                                               const float* __restrict__ E,
                                               const float* __restrict__ wT,
                                               float* __restrict__ F) {
  int e = blockIdx.x * 256 + threadIdx.x;
  float acc[32];
  float ev = E[e];
  #pragma unroll
  for (int b = 0; b < 32; ++b) acc[b] = ev;
  for (int k = 0; k < 128; ++k) {
    float cv = C[(size_t)k * 16384 + e];
    const float* wk = wT + k * 32;  // uniform -> s_load
    #pragma unroll
    for (int b = 0; b < 32; ++b) acc[b] = fmaf(-wk[b], cv, acc[b]);
  }
  #pragma unroll
  for (int b = 0; b < 32; ++b) F[(size_t)b * 16384 + e] = acc[b];
}

// ---------------------------------------------------------------------------
// K9: out[b] = xn[b] + LR * F[b] @ xn[b]. grid (32,4): m-quarter of 64. block 256.
__global__ __launch_bounds__(256, 1) void k9_out(const float* __restrict__ F,
                                                 const float* __restrict__ xn,
                                                 float* __restrict__ out) {
  int b = blockIdx.x;
  int mq = blockIdx.y;
  __shared__ __align__(16) float Ft[128 * 65];  // 33.3 KB
  __shared__ __align__(16) float Xt[64 * 65];   // 16.6 KB
  int t = threadIdx.x;
  int tx = t & 15, ty = t >> 4;
  int i0 = ty * 8, m0 = mq * 64 + tx * 4;
  float acc[8][4] = {};
  for (int jc = 0; jc < 128; jc += 64) {
    __syncthreads();
    for (int q = 0; q < 32; ++q) {
      int e = q * 256 + t;
      int i = e >> 6, jj = e & 63;
      Ft[i * 65 + jj] = F[(size_t)b * 16384 + i * 128 + jc + jj];
    }
    for (int q = 0; q < 16; ++q) {
      int e = q * 256 + t;
      int jj = e >> 6, mm = e & 63;
      Xt[jj * 65 + mm] = xn[(size_t)b * (Nn * Mm) + (jc + jj) * Mm + mq * 64 + mm];
    }
    __syncthreads();
    for (int jj = 0; jj < 64; ++jj) {
      float fi[8], xm[4];
      #pragma unroll
      for (int q = 0; q < 8; ++q) fi[q] = Ft[(i0 + q) * 65 + jj];
      #pragma unroll
      for (int q = 0; q < 4; ++q) xm[q] = Xt[jj * 65 + tx * 4 + q];
      #pragma unroll
      for (int qi = 0; qi < 8; ++qi)
        #pragma unroll
        for (int qj = 0; qj < 4; ++qj)
          acc[qi][qj] = fmaf(fi[qi], xm[qj], acc[qi][qj]);
    }
  }
  #pragma unroll
  for (int qi = 0; qi < 8; ++qi) {
    int i = i0 + qi;
    float4 xv = *(const float4*)&xn[(size_t)b * (Nn * Mm) + i * Mm + m0];
    float4 o;
    o.x = fmaf(LR, acc[qi][0], xv.x);
    o.y = fmaf(LR, acc[qi][1], xv.y);
    o.z = fmaf(LR, acc[qi][2], xv.z);
    o.w = fmaf(LR, acc[qi][3], xv.w);
    *(float4*)&out[(size_t)b * (Nn * Mm) + i * Mm + m0] = o;
  }
}

// ---------------------------------------------------------------------------
extern "C" void kernel_launch(void* const* d_in, const int* in_sizes, int n_in,
                              void* d_out, int out_size, void* d_ws, size_t ws_size,
                              hipStream_t stream) {
  const float* x = (const float*)d_in[0];     // (32,128,256)
  const float* P = (const float*)d_in[1];     // (128,128,128) EC_proto
  const float* cnt = (const float*)d_in[2];   // (128,)
  float* out = (float*)d_out;

  float* ws = (float*)d_ws;
  float* xn = ws;                               // 1048576
  float* C = xn + 1048576;                      // 129*16384 = 2113536 (c_k; slot 128 = e)
  float* G = C + 2113536;                       // 2097152
  float* S = G + 2097152;                       // 524288
  float* part = S + 524288;                     // 1048576
  float* F = part + 1048576;                    // 524288
  float* wT = F + 524288;                       // 4096
  float* Psum = wT + 4096;                      // 16384
  float* alpha = Psum + 16384;                  // 129
  float* gama = alpha + 129;                    // 128
  size_t need_bytes = (size_t)((gama + 128) - ws) * sizeof(float);
  if (ws_size < need_bytes) return;  // ~29.5 MB required

  hipLaunchKernelGGL(k0_scalars, dim3(1), dim3(128), 0, stream, cnt, alpha, gama);
  hipLaunchKernelGGL(k1_bn, dim3(128), dim3(256), 0, stream, x, xn);
  hipLaunchKernelGGL(k2a_psum, dim3(64), dim3(256), 0, stream, P, Psum);
  hipLaunchKernelGGL(k2b_buildD, dim3(129), dim3(256), 0, stream, P, Psum, alpha, C);
  hipLaunchKernelGGL(k3_invert, dim3(129), dim3(256), 0, stream, C, alpha);
  hipLaunchKernelGGL(k4_gram, dim3(128), dim3(256), 0, stream, C, G);
  hipLaunchKernelGGL(k5_S, dim3(32, 2), dim3(256), 0, stream, xn, S);
  hipLaunchKernelGGL(k6_partial, dim3(256), dim3(256), 0, stream, G, S, part);
  hipLaunchKernelGGL(k7_weights, dim3(32), dim3(256), 0, stream, part, gama, cnt, wT);
  hipLaunchKernelGGL(k8_F, dim3(64), dim3(256), 0, stream, C, C + (size_t)128 * 16384, wT, F);
  hipLaunchKernelGGL(k9_out, dim3(32, 4), dim3(256), 0, stream, F, xn, out);
}

// Round 3
// 221.829 us; speedup vs baseline: 2.3717x; 1.7289x over previous
//
#include <hip/hip_runtime.h>
#include <math.h>

// Problem constants (B,K,N,M) = (32,128,128,256)
#define Bb 32
#define Kk 128
#define Nn 128
#define Mm 256
#define EPS2 0.01f      // EPSILON^2
#define LAMBDA_S 0.1f
#define LR 0.01f
#define BN_EPS_C 1e-5f

// ---------------------------------------------------------------------------
// K0: scalars — total = sum(count), alpha[k] = c_alpha_k, alpha[128] = e_alpha,
// gama[k] = count/total. 1 block x 128 threads.
__global__ void k0_scalars(const float* __restrict__ cnt, float* __restrict__ alpha,
                           float* __restrict__ gama) {
  int t = threadIdx.x;  // 0..127
  float c = cnt[t];
  float s = c;
  #pragma unroll
  for (int o = 32; o > 0; o >>= 1) s += __shfl_down(s, o, 64);
  __shared__ float red[2];
  if ((t & 63) == 0) red[t >> 6] = s;
  __syncthreads();
  float total = red[0] + red[1];
  bool has = total > 1e-6f;
  float bk = (c != 0.0f) ? 1.0f : 0.0f;
  float cfix = c + (1.0f - bk);
  alpha[t] = (float)Nn / (cfix * EPS2) * bk;
  gama[t] = has ? (c / total) : 0.0f;
  if (t == 0) alpha[128] = has ? ((float)Nn / (EPS2 * total)) : 0.0f;
}

// ---------------------------------------------------------------------------
// K1: BatchNorm over (B, M) per channel n. grid 128, block 256 (one thread per m).
__global__ void k1_bn(const float* __restrict__ x, float* __restrict__ xn) {
  int n = blockIdx.x;
  int t = threadIdx.x;  // = m
  float s = 0.f, s2 = 0.f;
  #pragma unroll 4
  for (int b = 0; b < Bb; ++b) {
    float v = x[(size_t)b * (Nn * Mm) + n * Mm + t];
    s += v;
    s2 += v * v;
  }
  #pragma unroll
  for (int o = 32; o > 0; o >>= 1) {
    s += __shfl_down(s, o, 64);
    s2 += __shfl_down(s2, o, 64);
  }
  __shared__ float rs[4], rs2[4];
  if ((t & 63) == 0) { rs[t >> 6] = s; rs2[t >> 6] = s2; }
  __syncthreads();
  float S = rs[0] + rs[1] + rs[2] + rs[3];
  float S2 = rs2[0] + rs2[1] + rs2[2] + rs2[3];
  float mean = S * (1.0f / (Bb * Mm));
  float var = S2 * (1.0f / (Bb * Mm)) - mean * mean;
  float rstd = 1.0f / sqrtf(var + BN_EPS_C);
  #pragma unroll 4
  for (int b = 0; b < Bb; ++b) {
    size_t idx = (size_t)b * (Nn * Mm) + n * Mm + t;
    xn[idx] = (x[idx] - mean) * rstd;
  }
}

// ---------------------------------------------------------------------------
// K2a: Psum = sum_k EC_proto[k]. grid 64, block 256.
__global__ void k2a_psum(const float* __restrict__ P, float* __restrict__ Psum) {
  int e = blockIdx.x * 256 + threadIdx.x;
  float s = 0.f;
  #pragma unroll 8
  for (int k = 0; k < Kk; ++k) s += P[(size_t)k * 16384 + e];
  Psum[e] = s;
}

// ---------------------------------------------------------------------------
// K3 v3: blocked Gauss-Jordan inverse (nb=16), register-resident 8x8 tiles.
// Thread (ty,tx) owns rows ty*8..+8, cols tx*8..+8 in VGPRs. Per panel:
//  A) dump R rows (quad-swizzled, conflict-free) + pre-panel M (transposed),
//  B) wave 0 runs 16 pivot steps on 2-rows-per-lane copy (shfl broadcast,
//     no barriers, static reg indices), writes M back,
//  C) all waves: rank-16 update  a = (prow? 0 : a) + M·R ; panel-col threads
//     reload M. Fuses k2b init (a = alpha*src + I) and final alpha scale.
// grid 129 (block 128 = e-matrix from Psum), block 256.
#define SWZ(c) (((c) & 14) | (((c) & 1) << 4) | (((c) >> 4) & 1))

__global__ __launch_bounds__(256, 1) void k3_invert(
    const float* __restrict__ P, const float* __restrict__ Psum,
    const float* __restrict__ alpha, float* __restrict__ C) {
  __shared__ float Mt[16 * 132];   // M transposed: Mt[q*132 + row], 8.4 KB
  __shared__ float Rb[16 * 128];   // R rows, float4-quad bit0<->bit4 swizzle, 8 KB
  int blk = blockIdx.x;
  int t = threadIdx.x;
  int tx = t & 15, ty = t >> 4;
  float av = alpha[blk];
  const float* src = (blk < 128) ? (P + (size_t)blk * 16384) : Psum;

  // init a = av*src + I
  float a[8][8];
  #pragma unroll
  for (int i = 0; i < 8; ++i) {
    int row = ty * 8 + i;
    float4 p0 = *(const float4*)&src[row * 128 + tx * 8];
    float4 p1 = *(const float4*)&src[row * 128 + tx * 8 + 4];
    a[i][0] = av * p0.x; a[i][1] = av * p0.y; a[i][2] = av * p0.z; a[i][3] = av * p0.w;
    a[i][4] = av * p1.x; a[i][5] = av * p1.y; a[i][6] = av * p1.z; a[i][7] = av * p1.w;
    if (tx == ty) a[i][i] += 1.0f;
  }

  for (int kb = 0; kb < 8; ++kb) {
    int k0 = kb * 16;
    // --- Phase A: dumps ---
    if ((ty >> 1) == kb) {          // R: pre-panel pivot rows (full 128 cols)
      int d = ty & 1;
      #pragma unroll
      for (int i = 0; i < 8; ++i) {
        *(float4*)&Rb[(d * 8 + i) * 128 + SWZ(2 * tx) * 4] =
            make_float4(a[i][0], a[i][1], a[i][2], a[i][3]);
        *(float4*)&Rb[(d * 8 + i) * 128 + SWZ(2 * tx + 1) * 4] =
            make_float4(a[i][4], a[i][5], a[i][6], a[i][7]);
      }
    }
    if ((tx >> 1) == kb) {          // M pre-panel values, transposed
      int dh = tx & 1;
      #pragma unroll
      for (int i = 0; i < 8; ++i)
        #pragma unroll
        for (int j = 0; j < 8; ++j)
          Mt[(dh * 8 + j) * 132 + ty * 8 + i] = a[i][j];
    }
    __syncthreads();

    // --- Phase B: wave 0 factors the 128x16 panel (no barriers inside) ---
    if (t < 64) {
      int l = t;
      float m[2][16];
      #pragma unroll
      for (int d = 0; d < 2; ++d)
        #pragma unroll
        for (int j = 0; j < 16; ++j)
          m[d][j] = Mt[j * 132 + 2 * l + d];
      #pragma unroll
      for (int q = 0; q < 16; ++q) {
        int lq = (k0 + q) >> 1;           // uniform source lane
        float pr[16];
        #pragma unroll
        for (int j = 0; j < 16; ++j) pr[j] = __shfl(m[q & 1][j], lq, 64);
        float pinv = 1.0f / pr[q];
        #pragma unroll
        for (int d = 0; d < 2; ++d) {
          float f = m[d][q];
          bool isp = (2 * l + d == k0 + q);
          float g = isp ? (1.0f - pinv) : f * pinv;
          #pragma unroll
          for (int j = 0; j < 16; ++j) m[d][j] = fmaf(-g, pr[j], m[d][j]);
          m[d][q] = isp ? pinv : -g;
        }
      }
      #pragma unroll
      for (int d = 0; d < 2; ++d)
        #pragma unroll
        for (int j = 0; j < 16; ++j)
          Mt[j * 132 + 2 * l + d] = m[d][j];
    }
    __syncthreads();

    // --- Phase C: rank-16 trailing update ---
    if ((ty >> 1) == kb) {          // panel rows: old value dropped
      #pragma unroll
      for (int i = 0; i < 8; ++i)
        #pragma unroll
        for (int j = 0; j < 8; ++j) a[i][j] = 0.0f;
    }
    #pragma unroll
    for (int q = 0; q < 16; ++q) {
      float4 m0 = *(const float4*)&Mt[q * 132 + ty * 8];
      float4 m1 = *(const float4*)&Mt[q * 132 + ty * 8 + 4];
      float4 r0 = *(const float4*)&Rb[q * 128 + SWZ(2 * tx) * 4];
      float4 r1 = *(const float4*)&Rb[q * 128 + SWZ(2 * tx + 1) * 4];
      float mq[8] = {m0.x, m0.y, m0.z, m0.w, m1.x, m1.y, m1.z, m1.w};
      float rq[8] = {r0.x, r0.y, r0.z, r0.w, r1.x, r1.y, r1.z, r1.w};
      #pragma unroll
      for (int i = 0; i < 8; ++i)
        #pragma unroll
        for (int j = 0; j < 8; ++j)
          a[i][j] = fmaf(mq[i], rq[j], a[i][j]);
    }
    if ((tx >> 1) == kb) {          // panel cols: value IS M (reload)
      int dh = tx & 1;
      #pragma unroll
      for (int j = 0; j < 8; ++j) {
        float4 v0 = *(const float4*)&Mt[(dh * 8 + j) * 132 + ty * 8];
        float4 v1 = *(const float4*)&Mt[(dh * 8 + j) * 132 + ty * 8 + 4];
        a[0][j] = v0.x; a[1][j] = v0.y; a[2][j] = v0.z; a[3][j] = v0.w;
        a[4][j] = v1.x; a[5][j] = v1.y; a[6][j] = v1.z; a[7][j] = v1.w;
      }
    }
    __syncthreads();                // protect Mt/Rb before next panel's dumps
  }

  // scale by alpha and store
  float* dst = C + (size_t)blk * 16384;
  #pragma unroll
  for (int i = 0; i < 8; ++i) {
    int row = ty * 8 + i;
    float4 v0 = make_float4(av * a[i][0], av * a[i][1], av * a[i][2], av * a[i][3]);
    float4 v1 = make_float4(av * a[i][4], av * a[i][5], av * a[i][6], av * a[i][7]);
    *(float4*)&dst[row * 128 + tx * 8] = v0;
    *(float4*)&dst[row * 128 + tx * 8 + 4] = v1;
  }
}

// ---------------------------------------------------------------------------
// K4: G_k = c_k^T c_k. grid 128, block 256 (16x16 threads, 8x8 outputs each).
__global__ __launch_bounds__(256, 1) void k4_gram(const float* __restrict__ C,
                                                  float* __restrict__ G) {
  __shared__ __align__(16) float A[128 * 128];  // full c_k, 64 KB
  int k = blockIdx.x;
  int t = threadIdx.x;
  const float* src = C + (size_t)k * 16384;
  for (int c = 0; c < 64; ++c) A[c * 256 + t] = src[c * 256 + t];
  __syncthreads();
  int tx = t & 15, ty = t >> 4;
  int i0 = ty * 8, j0 = tx * 8;
  float acc[8][8] = {};
  for (int l = 0; l < 128; ++l) {
    float ai[8], bj[8];
    *(float4*)&ai[0] = *(const float4*)&A[l * 128 + i0];
    *(float4*)&ai[4] = *(const float4*)&A[l * 128 + i0 + 4];
    *(float4*)&bj[0] = *(const float4*)&A[l * 128 + j0];
    *(float4*)&bj[4] = *(const float4*)&A[l * 128 + j0 + 4];
    #pragma unroll
    for (int qi = 0; qi < 8; ++qi)
      #pragma unroll
      for (int qj = 0; qj < 8; ++qj)
        acc[qi][qj] = fmaf(ai[qi], bj[qj], acc[qi][qj]);
  }
  float* dst = G + (size_t)k * 16384;
  #pragma unroll
  for (int qi = 0; qi < 8; ++qi) {
    float4 v0 = make_float4(acc[qi][0], acc[qi][1], acc[qi][2], acc[qi][3]);
    float4 v1 = make_float4(acc[qi][4], acc[qi][5], acc[qi][6], acc[qi][7]);
    *(float4*)&dst[(i0 + qi) * 128 + j0] = v0;
    *(float4*)&dst[(i0 + qi) * 128 + j0 + 4] = v1;
  }
}

// ---------------------------------------------------------------------------
// K5: S_b = xn_b xn_b^T. grid (32,2): col-half of 64. block 256 (8x4 outputs/thread).
__global__ __launch_bounds__(256, 1) void k5_S(const float* __restrict__ xn,
                                               float* __restrict__ S) {
  int b = blockIdx.x;
  int jbase = blockIdx.y * 64;
  __shared__ __align__(16) float X[128 * 65];  // 33.3 KB, pad 65 breaks conflicts
  int t = threadIdx.x;
  int tx = t & 15, ty = t >> 4;
  float acc[8][4] = {};
  for (int mc = 0; mc < Mm; mc += 64) {
    __syncthreads();
    for (int c = 0; c < 32; ++c) {
      int e = c * 256 + t;
      int i = e >> 6, mm = e & 63;
      X[i * 65 + mm] = xn[(size_t)b * (Nn * Mm) + i * Mm + mc + mm];
    }
    __syncthreads();
    for (int mm = 0; mm < 64; ++mm) {
      float ai[8], bj[4];
      #pragma unroll
      for (int q = 0; q < 8; ++q) ai[q] = X[(ty * 8 + q) * 65 + mm];
      #pragma unroll
      for (int q = 0; q < 4; ++q) bj[q] = X[(jbase + tx * 4 + q) * 65 + mm];
      #pragma unroll
      for (int qi = 0; qi < 8; ++qi)
        #pragma unroll
        for (int qj = 0; qj < 4; ++qj)
          acc[qi][qj] = fmaf(ai[qi], bj[qj], acc[qi][qj]);
    }
  }
  float* dst = S + (size_t)b * 16384;
  #pragma unroll
  for (int qi = 0; qi < 8; ++qi) {
    float4 v = make_float4(acc[qi][0], acc[qi][1], acc[qi][2], acc[qi][3]);
    *(float4*)&dst[(ty * 8 + qi) * 128 + jbase + tx * 4] = v;
  }
}

// ---------------------------------------------------------------------------
// K6: partial[c][b][k] = sum over inner chunk c (64 of 16384) of G[k][.]*S[b][.].
// grid 256, block 256.
__global__ __launch_bounds__(256, 1) void k6_partial(const float* __restrict__ G,
                                                     const float* __restrict__ S,
                                                     float* __restrict__ part) {
  int c = blockIdx.x;
  int t = threadIdx.x;
  __shared__ float Gp[128 * 65];  // 33.3 KB
  __shared__ float Sp[32 * 65];   // 8.3 KB
  int off = c * 64;
  for (int q = 0; q < 32; ++q) {
    int e = q * 256 + t;
    int k = e >> 6, jj = e & 63;
    Gp[k * 65 + jj] = G[(size_t)k * 16384 + off + jj];
  }
  for (int q = 0; q < 8; ++q) {
    int e = q * 256 + t;
    int b = e >> 6, jj = e & 63;
    Sp[b * 65 + jj] = S[(size_t)b * 16384 + off + jj];
  }
  __syncthreads();
  int tk = t & 15, tb = t >> 4;  // k = tk + 16q (bank-friendly), b = tb*2 + bb
  float acc[2][8] = {};
  for (int jj = 0; jj < 64; ++jj) {
    float sv0 = Sp[(tb * 2) * 65 + jj];
    float sv1 = Sp[(tb * 2 + 1) * 65 + jj];
    float gv[8];
    #pragma unroll
    for (int q = 0; q < 8; ++q) gv[q] = Gp[(tk + 16 * q) * 65 + jj];
    #pragma unroll
    for (int q = 0; q < 8; ++q) {
      acc[0][q] = fmaf(sv0, gv[q], acc[0][q]);
      acc[1][q] = fmaf(sv1, gv[q], acc[1][q]);
    }
  }
  float* pout = part + (size_t)c * 4096;
  #pragma unroll
  for (int bb = 0; bb < 2; ++bb)
    #pragma unroll
    for (int q = 0; q < 8; ++q)
      pout[(tb * 2 + bb) * 128 + tk + 16 * q] = acc[bb][q];
}

// ---------------------------------------------------------------------------
// K7: reduce partials -> norm -> rescale to sum 10 -> softmax -> w[k][b]=gama*pi.
// grid 32 (one per b), block 256 (two c-halves per k; duplicated softmax math).
__global__ void k7_weights(const float* __restrict__ part, const float* __restrict__ gama,
                           const float* __restrict__ cnt, float* __restrict__ wT) {
  int b = blockIdx.x;
  int t = threadIdx.x;
  int k = t & 127, h = t >> 7;
  float s = 0.f;
  #pragma unroll 8
  for (int c = h * 128; c < h * 128 + 128; ++c)
    s += part[(size_t)c * 4096 + b * 128 + k];
  __shared__ float sh[256];
  sh[t] = s;
  __syncthreads();
  float norm2 = sh[k] + sh[k + 128];  // both halves compute identical values
  float norm = sqrtf(fmaxf(norm2, 0.0f));
  // sum over 256 threads = 2 * (sum over k)
  float r = norm;
  #pragma unroll
  for (int o = 32; o > 0; o >>= 1) r += __shfl_down(r, o, 64);
  __shared__ float red[4];
  if ((t & 63) == 0) red[t >> 6] = r;
  __syncthreads();
  float sumn = 0.5f * (red[0] + red[1] + red[2] + red[3]);
  float nr = 10.0f * norm / fmaxf(sumn, 1e-30f);
  float ex = expf(-LAMBDA_S * nr);
  float r2 = ex;
  #pragma unroll
  for (int o = 32; o > 0; o >>= 1) r2 += __shfl_down(r2, o, 64);
  __shared__ float red2[4];
  if ((t & 63) == 0) red2[t >> 6] = r2;
  __syncthreads();
  float sume = 0.5f * (red2[0] + red2[1] + red2[2] + red2[3]);
  float bk = (cnt[k] != 0.0f) ? 1.0f : 0.0f;
  float pi = (ex / sume) * bk;
  if (h == 0) wT[k * 32 + b] = gama[k] * pi;  // transposed for K8 scalar loads
}

// ---------------------------------------------------------------------------
// K8 v2: F[b] = e - sum_k w[b][k] * c_k. grid (64,4), block 256; each thread
// one (i,j) element x 8 b-accumulators -> 256 blocks keep all CUs busy.
__global__ __launch_bounds__(256, 1) void k8_F(const float* __restrict__ C,
                                               const float* __restrict__ E,
                                               const float* __restrict__ wT,
                                               float* __restrict__ F) {
  int e = blockIdx.x * 256 + threadIdx.x;
  int b0 = blockIdx.y * 8;
  float acc[8];
  float ev = E[e];
  #pragma unroll
  for (int b = 0; b < 8; ++b) acc[b] = ev;
  for (int k = 0; k < 128; ++k) {
    float cv = C[(size_t)k * 16384 + e];
    const float* wk = wT + k * 32 + b0;  // uniform -> s_load
    #pragma unroll
    for (int b = 0; b < 8; ++b) acc[b] = fmaf(-wk[b], cv, acc[b]);
  }
  #pragma unroll
  for (int b = 0; b < 8; ++b) F[(size_t)(b0 + b) * 16384 + e] = acc[b];
}

// ---------------------------------------------------------------------------
// K9: out[b] = xn[b] + LR * F[b] @ xn[b]. grid (32,4): m-quarter of 64. block 256.
__global__ __launch_bounds__(256, 1) void k9_out(const float* __restrict__ F,
                                                 const float* __restrict__ xn,
                                                 float* __restrict__ out) {
  int b = blockIdx.x;
  int mq = blockIdx.y;
  __shared__ __align__(16) float Ft[128 * 65];  // 33.3 KB
  __shared__ __align__(16) float Xt[64 * 65];   // 16.6 KB
  int t = threadIdx.x;
  int tx = t & 15, ty = t >> 4;
  int i0 = ty * 8, m0 = mq * 64 + tx * 4;
  float acc[8][4] = {};
  for (int jc = 0; jc < 128; jc += 64) {
    __syncthreads();
    for (int q = 0; q < 32; ++q) {
      int e = q * 256 + t;
      int i = e >> 6, jj = e & 63;
      Ft[i * 65 + jj] = F[(size_t)b * 16384 + i * 128 + jc + jj];
    }
    for (int q = 0; q < 16; ++q) {
      int e = q * 256 + t;
      int jj = e >> 6, mm = e & 63;
      Xt[jj * 65 + mm] = xn[(size_t)b * (Nn * Mm) + (jc + jj) * Mm + mq * 64 + mm];
    }
    __syncthreads();
    for (int jj = 0; jj < 64; ++jj) {
      float fi[8], xm[4];
      #pragma unroll
      for (int q = 0; q < 8; ++q) fi[q] = Ft[(i0 + q) * 65 + jj];
      #pragma unroll
      for (int q = 0; q < 4; ++q) xm[q] = Xt[jj * 65 + tx * 4 + q];
      #pragma unroll
      for (int qi = 0; qi < 8; ++qi)
        #pragma unroll
        for (int qj = 0; qj < 4; ++qj)
          acc[qi][qj] = fmaf(fi[qi], xm[qj], acc[qi][qj]);
    }
  }
  #pragma unroll
  for (int qi = 0; qi < 8; ++qi) {
    int i = i0 + qi;
    float4 xv = *(const float4*)&xn[(size_t)b * (Nn * Mm) + i * Mm + m0];
    float4 o;
    o.x = fmaf(LR, acc[qi][0], xv.x);
    o.y = fmaf(LR, acc[qi][1], xv.y);
    o.z = fmaf(LR, acc[qi][2], xv.z);
    o.w = fmaf(LR, acc[qi][3], xv.w);
    *(float4*)&out[(size_t)b * (Nn * Mm) + i * Mm + m0] = o;
  }
}

// ---------------------------------------------------------------------------
extern "C" void kernel_launch(void* const* d_in, const int* in_sizes, int n_in,
                              void* d_out, int out_size, void* d_ws, size_t ws_size,
                              hipStream_t stream) {
  const float* x = (const float*)d_in[0];     // (32,128,256)
  const float* P = (const float*)d_in[1];     // (128,128,128) EC_proto
  const float* cnt = (const float*)d_in[2];   // (128,)
  float* out = (float*)d_out;

  float* ws = (float*)d_ws;
  float* xn = ws;                               // 1048576
  float* C = xn + 1048576;                      // 129*16384 = 2113536 (c_k; slot 128 = e)
  float* G = C + 2113536;                       // 2097152
  float* S = G + 2097152;                       // 524288
  float* part = S + 524288;                     // 1048576
  float* F = part + 1048576;                    // 524288
  float* wT = F + 524288;                       // 4096
  float* Psum = wT + 4096;                      // 16384
  float* alpha = Psum + 16384;                  // 129
  float* gama = alpha + 129;                    // 128
  size_t need_bytes = (size_t)((gama + 128) - ws) * sizeof(float);
  if (ws_size < need_bytes) return;  // ~29.5 MB required

  hipLaunchKernelGGL(k0_scalars, dim3(1), dim3(128), 0, stream, cnt, alpha, gama);
  hipLaunchKernelGGL(k1_bn, dim3(128), dim3(256), 0, stream, x, xn);
  hipLaunchKernelGGL(k2a_psum, dim3(64), dim3(256), 0, stream, P, Psum);
  hipLaunchKernelGGL(k3_invert, dim3(129), dim3(256), 0, stream, P, Psum, alpha, C);
  hipLaunchKernelGGL(k4_gram, dim3(128), dim3(256), 0, stream, C, G);
  hipLaunchKernelGGL(k5_S, dim3(32, 2), dim3(256), 0, stream, xn, S);
  hipLaunchKernelGGL(k6_partial, dim3(256), dim3(256), 0, stream, G, S, part);
  hipLaunchKernelGGL(k7_weights, dim3(32), dim3(256), 0, stream, part, gama, cnt, wT);
  hipLaunchKernelGGL(k8_F, dim3(64, 4), dim3(256), 0, stream, C, C + (size_t)128 * 16384, wT, F);
  hipLaunchKernelGGL(k9_out, dim3(32, 4), dim3(256), 0, stream, F, xn, out);
}